// Round 8
// baseline (63.979 us; speedup 1.0000x reference)
//
#include <hip/hip_runtime.h>

typedef __bf16 bf16x8 __attribute__((ext_vector_type(8)));
typedef float f32x4 __attribute__((ext_vector_type(4)));
typedef unsigned short u16x8 __attribute__((ext_vector_type(8)));
typedef unsigned short u16x4 __attribute__((ext_vector_type(4)));

#define B_ 32
#define CC 512
#define HW 192
#define C8_ 64
#define NTRI 528
#define TILE_B 24576      // one 192x64 bf16 tile, 128B rows
#define SMEM_BYTES 152064 // 3 dbuf pairs (147456) + colbuf 1536 + rowbuf 3072

__device__ inline unsigned short f2bf(float f) {
    unsigned u = __float_as_uint(f);
    unsigned r = (u + 0x7FFFu + ((u >> 16) & 1u)) >> 16;
    return (unsigned short)r;
}

__device__ inline void gload16(const void* g, void* l) {
    __builtin_amdgcn_global_load_lds(
        (const __attribute__((address_space(1))) unsigned*)g,
        (__attribute__((address_space(3))) unsigned*)l,
        16, 0, 0);
}

// ---------------- Kernel 1: x [B][C][HW] f32 -> xt [B][HW][C] bf16 ----------
__global__ void k_transpose(const float* __restrict__ x,
                            unsigned short* __restrict__ xt) {
    __shared__ unsigned short tile[64 * 64];
    int b = blockIdx.x / 3, mt = blockIdx.x % 3;
    int m0 = mt * 64, c0 = blockIdx.y * 64;
    int t = threadIdx.x;
    const float* xb = x + (size_t)b * CC * HW + (size_t)c0 * HW + m0;

    int mq = t & 15, cl0 = t >> 4;
    int sw = (mq & 7) << 3;
    #pragma unroll
    for (int rd = 0; rd < 4; ++rd) {
        int cl = rd * 16 + cl0;
        f32x4 v = *(const f32x4*)(xb + cl * HW + mq * 4);
        #pragma unroll
        for (int e = 0; e < 4; ++e)
            tile[(mq * 4 + e) * 64 + (cl ^ sw)] = f2bf(v[e]);
    }
    __syncthreads();
    unsigned short* xo = xt + ((size_t)b * HW + m0) * CC + c0;
    int kc = t & 7, mr0 = t >> 3;
    #pragma unroll
    for (int rd = 0; rd < 2; ++rd) {
        int mr = rd * 32 + mr0;
        u16x8 v = *(const u16x8*)&tile[mr * 64 + ((kc << 3) ^ (((mr >> 2) & 7) << 3))];
        *(u16x8*)(xo + (size_t)mr * CC + kc * 8) = v;
    }
}

// ---------------- Kernel 2: precast Wq/Wk -> bf16 ---------------------------
__global__ void wcvt(const float* __restrict__ Wq, const float* __restrict__ Wk,
                     unsigned short* __restrict__ wqb, unsigned short* __restrict__ wkb) {
    const float* src = (blockIdx.x < 32) ? Wq : Wk;
    unsigned short* dst = (blockIdx.x < 32) ? wqb : wkb;
    int base = (blockIdx.x & 31) * 1024 + threadIdx.x * 4;
    f32x4 a = *(const f32x4*)(src + base);
    u16x4 o;
    #pragma unroll
    for (int e = 0; e < 4; ++e) o[e] = f2bf(a[e]);
    *(u16x4*)(dst + base) = o;
}

// ---------------- Kernel 3: q/k projections via MFMA ------------------------
__global__ __launch_bounds__(256) void pam_qk(
        const unsigned short* __restrict__ xt,
        const unsigned short* __restrict__ wqb, const unsigned short* __restrict__ wkb,
        const float* __restrict__ bq, const float* __restrict__ bk,
        unsigned short* __restrict__ qo, unsigned short* __restrict__ ko) {
    int b = blockIdx.x, m0 = blockIdx.y * 48;
    int tid = threadIdx.x, w = tid >> 6, lane = tid & 63;
    int l15 = lane & 15, lq = lane >> 4;
    int qc = w * 16 + l15;

    f32x4 accq[3], acck[3];
    #pragma unroll
    for (int i = 0; i < 3; ++i) {
        accq[i] = (f32x4){0.f, 0.f, 0.f, 0.f};
        acck[i] = (f32x4){0.f, 0.f, 0.f, 0.f};
    }

    const unsigned short* xb = xt + ((size_t)b * HW + m0) * CC;
    const unsigned short* wqp = wqb + (size_t)qc * CC;
    const unsigned short* wkp = wkb + (size_t)qc * CC;

    for (int kt = 0; kt < 16; ++kt) {
        int ko8 = kt * 32 + lq * 8;
        bf16x8 wqf = *(const bf16x8*)(wqp + ko8);
        bf16x8 wkf = *(const bf16x8*)(wkp + ko8);
        bf16x8 af[3];
        #pragma unroll
        for (int i = 0; i < 3; ++i)
            af[i] = *(const bf16x8*)(xb + (i * 16 + l15) * CC + ko8);
        #pragma unroll
        for (int i = 0; i < 3; ++i) {
            accq[i] = __builtin_amdgcn_mfma_f32_16x16x32_bf16(af[i], wqf, accq[i], 0, 0, 0);
            acck[i] = __builtin_amdgcn_mfma_f32_16x16x32_bf16(af[i], wkf, acck[i], 0, 0, 0);
        }
    }

    float bqv = bq[qc], bkv = bk[qc];
    #pragma unroll
    for (int i = 0; i < 3; ++i) {
        #pragma unroll
        for (int r = 0; r < 4; ++r) {
            int m = m0 + i * 16 + lq * 4 + r;
            qo[((size_t)b * HW + m) * C8_ + qc] = f2bf(accq[i][r] + bqv);
            ko[((size_t)b * HW + m) * C8_ + qc] = f2bf(acck[i][r] + bkv);
        }
    }
}

// ---------------- Kernel 4: energy = q k^T per batch, fused row-max ---------
__global__ __launch_bounds__(256) void pam_energy(
        const unsigned short* __restrict__ qo,
        const unsigned short* __restrict__ ko,
        float* __restrict__ out) {
    int b = blockIdx.x, m0 = blockIdx.y * 48;
    int tid = threadIdx.x, w = tid >> 6, lane = tid & 63;
    int l15 = lane & 15, lq = lane >> 4;
    int n0 = w * 48;

    f32x4 acc[3][3];
    #pragma unroll
    for (int i = 0; i < 3; ++i)
        #pragma unroll
        for (int j = 0; j < 3; ++j)
            acc[i][j] = (f32x4){0.f, 0.f, 0.f, 0.f};

    const unsigned short* qb = qo + ((size_t)b * HW + m0) * C8_;
    const unsigned short* kb = ko + ((size_t)b * HW + n0) * C8_;

    #pragma unroll
    for (int kt = 0; kt < 2; ++kt) {
        int ko8 = kt * 32 + lq * 8;
        bf16x8 af[3], bfr[3];
        #pragma unroll
        for (int i = 0; i < 3; ++i)
            af[i] = *(const bf16x8*)(qb + (i * 16 + l15) * C8_ + ko8);
        #pragma unroll
        for (int j = 0; j < 3; ++j)
            bfr[j] = *(const bf16x8*)(kb + (j * 16 + l15) * C8_ + ko8);
        #pragma unroll
        for (int i = 0; i < 3; ++i)
            #pragma unroll
            for (int j = 0; j < 3; ++j)
                acc[i][j] = __builtin_amdgcn_mfma_f32_16x16x32_bf16(af[i], bfr[j], acc[i][j], 0, 0, 0);
    }

    __shared__ float red[4][48];
    #pragma unroll
    for (int i = 0; i < 3; ++i) {
        float rm[4];
        #pragma unroll
        for (int r = 0; r < 4; ++r) rm[r] = -1e30f;
        #pragma unroll
        for (int j = 0; j < 3; ++j)
            #pragma unroll
            for (int r = 0; r < 4; ++r)
                rm[r] = fmaxf(rm[r], acc[i][j][r]);
        #pragma unroll
        for (int msk = 1; msk <= 8; msk <<= 1)
            #pragma unroll
            for (int r = 0; r < 4; ++r)
                rm[r] = fmaxf(rm[r], __shfl_xor(rm[r], msk));
        if (l15 == 0) {
            #pragma unroll
            for (int r = 0; r < 4; ++r)
                red[w][i * 16 + lq * 4 + r] = rm[r];
        }
    }
    __syncthreads();
    if (tid < 48) {
        float v = fmaxf(fmaxf(red[0][tid], red[1][tid]),
                        fmaxf(red[2][tid], red[3][tid]));
        out[((size_t)B_ * B_ + b) * HW + m0 + tid] = v;
    }
}

// ---------------- Kernel 5: Gram, triple-buffer + counted vmcnt -------------
// 528 blocks x 512 thr (8 waves 2x4). BK=64, 3 LDS buffer pairs, stage 2 ahead
// (12 loads in flight), s_waitcnt vmcnt(6) + raw s_barrier per K-step — loads
// stay in flight across barriers (no vmcnt(0) drain in the main loop).
__global__ __launch_bounds__(512) void gram(const unsigned short* __restrict__ xt,
                                            float* __restrict__ out) {
    extern __shared__ char smem[];
    float* colbuf = (float*)(smem + 6 * TILE_B);           // [2][192]
    float* rowbuf = (float*)(smem + 6 * TILE_B + 1536);    // [4][192]

    int tid = threadIdx.x;
    int bid = (blockIdx.x & 7) * 66 + (blockIdx.x >> 3);   // 528 = 8*66
    int idx = bid, g = 0;
    while (idx >= B_ - g) { idx -= B_ - g; ++g; }
    int p = g + idx;

    const unsigned short* xg = xt + (size_t)g * HW * CC;
    const unsigned short* xp = xt + (size_t)p * HW * CC;

    int w = tid >> 6, lane = tid & 63;
    int wr = w >> 2, wc = w & 3;                // 2 x 4 wave grid
    int l15 = lane & 15, lq = lane >> 4;

    int l8 = lane >> 3, s8 = lane & 7;
    const unsigned short* agp = xg + (size_t)(24 * w + l8) * CC + ((s8 ^ l8) << 3);
    const unsigned short* bgp = xp + (size_t)(24 * w + l8) * CC + ((s8 ^ l8) << 3);
    unsigned ldsw = (unsigned)(24 * w) * 128;

    unsigned aoff[6], boff[3];
    #pragma unroll
    for (int i = 0; i < 6; ++i) {
        int row = wr * 96 + i * 16 + l15;
        aoff[i] = row * 128 + ((unsigned)(lq ^ (row & 7)) << 4);
    }
    #pragma unroll
    for (int j = 0; j < 3; ++j) {
        int row = wc * 48 + j * 16 + l15;
        boff[j] = row * 128 + ((unsigned)(lq ^ (row & 7)) << 4);
    }

    f32x4 acc[6][3];
    #pragma unroll
    for (int i = 0; i < 6; ++i)
        #pragma unroll
        for (int j = 0; j < 3; ++j)
            acc[i][j] = (f32x4){0.f, 0.f, 0.f, 0.f};

    // buffer b occupies [b*2*TILE_B, b*2*TILE_B + 2*TILE_B): A-tile then B-tile
    #define STAGE(buf, k0)                                                     \
        {                                                                      \
            char* ab = smem + (buf) * (2 * TILE_B) + ldsw;                     \
            char* bb = ab + TILE_B;                                            \
            _Pragma("unroll")                                                  \
            for (int ci = 0; ci < 3; ++ci) {                                   \
                gload16(agp + (k0) + ci * 8 * CC, ab + ci * 1024);             \
                gload16(bgp + (k0) + ci * 8 * CC, bb + ci * 1024);             \
            }                                                                  \
        }

    #define COMPUTE(buf)                                                       \
        {                                                                      \
            const char* Ab = smem + (buf) * (2 * TILE_B);                      \
            const char* Bb = Ab + TILE_B;                                      \
            _Pragma("unroll")                                                  \
            for (int kx = 0; kx < 128; kx += 64) {                             \
                bf16x8 af[6], bfr[3];                                          \
                _Pragma("unroll")                                              \
                for (int i = 0; i < 6; ++i)                                    \
                    af[i] = *(const bf16x8*)(Ab + (aoff[i] ^ kx));             \
                _Pragma("unroll")                                              \
                for (int j = 0; j < 3; ++j)                                    \
                    bfr[j] = *(const bf16x8*)(Bb + (boff[j] ^ kx));            \
                _Pragma("unroll")                                              \
                for (int i = 0; i < 6; ++i)                                    \
                    _Pragma("unroll")                                          \
                    for (int j = 0; j < 3; ++j)                                \
                        acc[i][j] = __builtin_amdgcn_mfma_f32_16x16x32_bf16(   \
                            af[i], bfr[j], acc[i][j], 0, 0, 0);                \
            }                                                                  \
        }

    #define WAIT6() asm volatile("s_waitcnt vmcnt(6)" ::: "memory")
    #define WAIT0() asm volatile("s_waitcnt vmcnt(0)" ::: "memory")
    #define BAR()   { __builtin_amdgcn_sched_barrier(0); __builtin_amdgcn_s_barrier(); }

    STAGE(0, 0);
    STAGE(1, 64);                       // 12 loads in flight

    WAIT6(); BAR(); STAGE(2, 2 * 64); COMPUTE(0);   // kt=0
    WAIT6(); BAR(); STAGE(0, 3 * 64); COMPUTE(1);   // kt=1
    WAIT6(); BAR(); STAGE(1, 4 * 64); COMPUTE(2);   // kt=2
    WAIT6(); BAR(); STAGE(2, 5 * 64); COMPUTE(0);   // kt=3
    WAIT6(); BAR(); STAGE(0, 6 * 64); COMPUTE(1);   // kt=4
    WAIT6(); BAR(); STAGE(1, 7 * 64); COMPUTE(2);   // kt=5
    WAIT6(); BAR();                   COMPUTE(0);   // kt=6 (stage(7) in flight)
    WAIT0(); BAR();                   COMPUTE(1);   // kt=7 (full drain)

    // ---- epilogue: col-max over m -> out[g][p][n]; row-max over n -> out[p][g][m]
    #pragma unroll
    for (int j = 0; j < 3; ++j) {
        float cm = -1e30f;
        #pragma unroll
        for (int i = 0; i < 6; ++i)
            #pragma unroll
            for (int r = 0; r < 4; ++r)
                cm = fmaxf(cm, acc[i][j][r]);
        cm = fmaxf(cm, __shfl_xor(cm, 16));
        cm = fmaxf(cm, __shfl_xor(cm, 32));
        if (lane < 16) colbuf[wr * HW + wc * 48 + j * 16 + l15] = cm;
    }
    #pragma unroll
    for (int i = 0; i < 6; ++i) {
        float rm[4];
        #pragma unroll
        for (int r = 0; r < 4; ++r) rm[r] = -1e30f;
        #pragma unroll
        for (int j = 0; j < 3; ++j)
            #pragma unroll
            for (int r = 0; r < 4; ++r)
                rm[r] = fmaxf(rm[r], acc[i][j][r]);
        #pragma unroll
        for (int msk = 1; msk <= 8; msk <<= 1)
            #pragma unroll
            for (int r = 0; r < 4; ++r)
                rm[r] = fmaxf(rm[r], __shfl_xor(rm[r], msk));
        if (l15 == 0) {
            #pragma unroll
            for (int r = 0; r < 4; ++r)
                rowbuf[wc * HW + wr * 96 + i * 16 + lq * 4 + r] = rm[r];
        }
    }
    __syncthreads();
    if (tid < HW) {
        float cmax = fmaxf(colbuf[tid], colbuf[HW + tid]);
        out[((size_t)g * B_ + p) * HW + tid] = cmax;
        float rmax = fmaxf(fmaxf(rowbuf[tid], rowbuf[HW + tid]),
                           fmaxf(rowbuf[2 * HW + tid], rowbuf[3 * HW + tid]));
        out[((size_t)p * B_ + g) * HW + tid] = rmax;
    }
}

extern "C" void kernel_launch(void* const* d_in, const int* in_sizes, int n_in,
                              void* d_out, int out_size, void* d_ws, size_t ws_size,
                              hipStream_t stream) {
    (void)in_sizes; (void)n_in; (void)out_size; (void)ws_size;
    const float* x  = (const float*)d_in[0];
    const float* Wq = (const float*)d_in[1];
    const float* bq = (const float*)d_in[2];
    const float* Wk = (const float*)d_in[3];
    const float* bk = (const float*)d_in[4];
    float* out = (float*)d_out;

    char* ws = (char*)d_ws;
    unsigned short* xt  = (unsigned short*)ws;                       // 6291456 B
    unsigned short* wqb = (unsigned short*)(ws + 6291456);           // 65536 B
    unsigned short* wkb = (unsigned short*)(ws + 6291456 + 65536);   // 65536 B
    unsigned short* qbuf = (unsigned short*)(ws + 6291456 + 131072); // 786432 B
    unsigned short* kbuf = (unsigned short*)(ws + 6291456 + 131072 + 786432);

    hipFuncSetAttribute((const void*)gram,
                        hipFuncAttributeMaxDynamicSharedMemorySize, SMEM_BYTES);

    k_transpose<<<dim3(96, 8), dim3(256), 0, stream>>>(x, xt);
    wcvt<<<dim3(64), dim3(256), 0, stream>>>(Wq, Wk, wqb, wkb);
    pam_qk<<<dim3(32, 4), dim3(256), 0, stream>>>(xt, wqb, wkb, bq, bk, qbuf, kbuf);
    pam_energy<<<dim3(32, 4), dim3(256), 0, stream>>>(qbuf, kbuf, out);
    gram<<<dim3(NTRI), dim3(512), SMEM_BYTES, stream>>>(xt, out);
}

// Round 9
// 60.329 us; speedup vs baseline: 1.0605x; 1.0605x over previous
//
#include <hip/hip_runtime.h>

typedef __bf16 bf16x8 __attribute__((ext_vector_type(8)));
typedef float f32x4 __attribute__((ext_vector_type(4)));
typedef unsigned short u16x8 __attribute__((ext_vector_type(8)));
typedef unsigned short u16x4 __attribute__((ext_vector_type(4)));

#define B_ 32
#define CC 512
#define HW 192
#define C8_ 64
#define NTRI 528
#define PAIR_B 24576      // one buffer: A(192x32) + B(192x32) bf16, 64B rows
#define SMEM_BYTES 73728  // 3 buffers; epilogue bufs alias buffer 1

__device__ inline unsigned short f2bf(float f) {
    unsigned u = __float_as_uint(f);
    unsigned r = (u + 0x7FFFu + ((u >> 16) & 1u)) >> 16;
    return (unsigned short)r;
}

__device__ inline void gload16(const void* g, void* l) {
    __builtin_amdgcn_global_load_lds(
        (const __attribute__((address_space(1))) unsigned*)g,
        (__attribute__((address_space(3))) unsigned*)l,
        16, 0, 0);
}

// ---------------- Kernel 1: x [B][C][HW] f32 -> xt [B][HW][C] bf16 ----------
__global__ void k_transpose(const float* __restrict__ x,
                            unsigned short* __restrict__ xt) {
    __shared__ unsigned short tile[64 * 64];
    int b = blockIdx.x / 3, mt = blockIdx.x % 3;
    int m0 = mt * 64, c0 = blockIdx.y * 64;
    int t = threadIdx.x;
    const float* xb = x + (size_t)b * CC * HW + (size_t)c0 * HW + m0;

    int mq = t & 15, cl0 = t >> 4;
    int sw = (mq & 7) << 3;
    #pragma unroll
    for (int rd = 0; rd < 4; ++rd) {
        int cl = rd * 16 + cl0;
        f32x4 v = *(const f32x4*)(xb + cl * HW + mq * 4);
        #pragma unroll
        for (int e = 0; e < 4; ++e)
            tile[(mq * 4 + e) * 64 + (cl ^ sw)] = f2bf(v[e]);
    }
    __syncthreads();
    unsigned short* xo = xt + ((size_t)b * HW + m0) * CC + c0;
    int kc = t & 7, mr0 = t >> 3;
    #pragma unroll
    for (int rd = 0; rd < 2; ++rd) {
        int mr = rd * 32 + mr0;
        u16x8 v = *(const u16x8*)&tile[mr * 64 + ((kc << 3) ^ (((mr >> 2) & 7) << 3))];
        *(u16x8*)(xo + (size_t)mr * CC + kc * 8) = v;
    }
}

// ---------------- Kernel 2: precast Wq/Wk -> bf16 ---------------------------
__global__ void wcvt(const float* __restrict__ Wq, const float* __restrict__ Wk,
                     unsigned short* __restrict__ wqb, unsigned short* __restrict__ wkb) {
    const float* src = (blockIdx.x < 32) ? Wq : Wk;
    unsigned short* dst = (blockIdx.x < 32) ? wqb : wkb;
    int base = (blockIdx.x & 31) * 1024 + threadIdx.x * 4;
    f32x4 a = *(const f32x4*)(src + base);
    u16x4 o;
    #pragma unroll
    for (int e = 0; e < 4; ++e) o[e] = f2bf(a[e]);
    *(u16x4*)(dst + base) = o;
}

// ---------------- Kernel 3: q/k projections via MFMA ------------------------
__global__ __launch_bounds__(256) void pam_qk(
        const unsigned short* __restrict__ xt,
        const unsigned short* __restrict__ wqb, const unsigned short* __restrict__ wkb,
        const float* __restrict__ bq, const float* __restrict__ bk,
        unsigned short* __restrict__ qo, unsigned short* __restrict__ ko) {
    int b = blockIdx.x, m0 = blockIdx.y * 48;
    int tid = threadIdx.x, w = tid >> 6, lane = tid & 63;
    int l15 = lane & 15, lq = lane >> 4;
    int qc = w * 16 + l15;

    f32x4 accq[3], acck[3];
    #pragma unroll
    for (int i = 0; i < 3; ++i) {
        accq[i] = (f32x4){0.f, 0.f, 0.f, 0.f};
        acck[i] = (f32x4){0.f, 0.f, 0.f, 0.f};
    }

    const unsigned short* xb = xt + ((size_t)b * HW + m0) * CC;
    const unsigned short* wqp = wqb + (size_t)qc * CC;
    const unsigned short* wkp = wkb + (size_t)qc * CC;

    for (int kt = 0; kt < 16; ++kt) {
        int ko8 = kt * 32 + lq * 8;
        bf16x8 wqf = *(const bf16x8*)(wqp + ko8);
        bf16x8 wkf = *(const bf16x8*)(wkp + ko8);
        bf16x8 af[3];
        #pragma unroll
        for (int i = 0; i < 3; ++i)
            af[i] = *(const bf16x8*)(xb + (i * 16 + l15) * CC + ko8);
        #pragma unroll
        for (int i = 0; i < 3; ++i) {
            accq[i] = __builtin_amdgcn_mfma_f32_16x16x32_bf16(af[i], wqf, accq[i], 0, 0, 0);
            acck[i] = __builtin_amdgcn_mfma_f32_16x16x32_bf16(af[i], wkf, acck[i], 0, 0, 0);
        }
    }

    float bqv = bq[qc], bkv = bk[qc];
    #pragma unroll
    for (int i = 0; i < 3; ++i) {
        #pragma unroll
        for (int r = 0; r < 4; ++r) {
            int m = m0 + i * 16 + lq * 4 + r;
            qo[((size_t)b * HW + m) * C8_ + qc] = f2bf(accq[i][r] + bqv);
            ko[((size_t)b * HW + m) * C8_ + qc] = f2bf(acck[i][r] + bkv);
        }
    }
}

// ---------------- Kernel 4: energy = q k^T per batch, fused row-max ---------
__global__ __launch_bounds__(256) void pam_energy(
        const unsigned short* __restrict__ qo,
        const unsigned short* __restrict__ ko,
        float* __restrict__ out) {
    int b = blockIdx.x, m0 = blockIdx.y * 48;
    int tid = threadIdx.x, w = tid >> 6, lane = tid & 63;
    int l15 = lane & 15, lq = lane >> 4;
    int n0 = w * 48;

    f32x4 acc[3][3];
    #pragma unroll
    for (int i = 0; i < 3; ++i)
        #pragma unroll
        for (int j = 0; j < 3; ++j)
            acc[i][j] = (f32x4){0.f, 0.f, 0.f, 0.f};

    const unsigned short* qb = qo + ((size_t)b * HW + m0) * C8_;
    const unsigned short* kb = ko + ((size_t)b * HW + n0) * C8_;

    #pragma unroll
    for (int kt = 0; kt < 2; ++kt) {
        int ko8 = kt * 32 + lq * 8;
        bf16x8 af[3], bfr[3];
        #pragma unroll
        for (int i = 0; i < 3; ++i)
            af[i] = *(const bf16x8*)(qb + (i * 16 + l15) * C8_ + ko8);
        #pragma unroll
        for (int j = 0; j < 3; ++j)
            bfr[j] = *(const bf16x8*)(kb + (j * 16 + l15) * C8_ + ko8);
        #pragma unroll
        for (int i = 0; i < 3; ++i)
            #pragma unroll
            for (int j = 0; j < 3; ++j)
                acc[i][j] = __builtin_amdgcn_mfma_f32_16x16x32_bf16(af[i], bfr[j], acc[i][j], 0, 0, 0);
    }

    __shared__ float red[4][48];
    #pragma unroll
    for (int i = 0; i < 3; ++i) {
        float rm[4];
        #pragma unroll
        for (int r = 0; r < 4; ++r) rm[r] = -1e30f;
        #pragma unroll
        for (int j = 0; j < 3; ++j)
            #pragma unroll
            for (int r = 0; r < 4; ++r)
                rm[r] = fmaxf(rm[r], acc[i][j][r]);
        #pragma unroll
        for (int msk = 1; msk <= 8; msk <<= 1)
            #pragma unroll
            for (int r = 0; r < 4; ++r)
                rm[r] = fmaxf(rm[r], __shfl_xor(rm[r], msk));
        if (l15 == 0) {
            #pragma unroll
            for (int r = 0; r < 4; ++r)
                red[w][i * 16 + lq * 4 + r] = rm[r];
        }
    }
    __syncthreads();
    if (tid < 48) {
        float v = fmaxf(fmaxf(red[0][tid], red[1][tid]),
                        fmaxf(red[2][tid], red[3][tid]));
        out[((size_t)B_ * B_ + b) * HW + m0 + tid] = v;
    }
}

// ---------------- Kernel 5: Gram, BK=32, 3-buf, 2 blocks/CU -----------------
// 528 blocks x 512 thr (8 waves 2x4). Waves 0-3 stage A-tile, 4-7 stage B.
// 16 K-steps; counted vmcnt(3); one s_barrier per step. LDS 73.7 KB ->
// two blocks co-resident per CU (launch_bounds caps VGPR at 128).
__global__ __launch_bounds__(512, 4) void gram(const unsigned short* __restrict__ xt,
                                               float* __restrict__ out) {
    extern __shared__ char smem[];

    int tid = threadIdx.x;
    int bid = (blockIdx.x & 7) * 66 + (blockIdx.x >> 3);   // 528 = 8*66
    int idx = bid, g = 0;
    while (idx >= B_ - g) { idx -= B_ - g; ++g; }
    int p = g + idx;

    const unsigned short* xg = xt + (size_t)g * HW * CC;
    const unsigned short* xp = xt + (size_t)p * HW * CC;

    int w = tid >> 6, lane = tid & 63;
    int wr = w >> 2, wc = w & 3;                // 2 x 4 wave grid
    int l15 = lane & 15, lq = lane >> 4;

    // staging: waves 0-3 stage A rows [48w,48w+48), waves 4-7 stage B rows.
    // Round ci covers 16 rows; lane -> row = base + ci*16 + (lane>>2), slot lane&3.
    // Logical k-chunk at phys slot s is s ^ ((row>>1)&3) = s ^ ((lane>>3)&3).
    int rowbase = (w & 3) * 48;
    const unsigned short* gsrc = (w < 4 ? xg : xp)
        + (size_t)(rowbase + (lane >> 2)) * CC
        + (((lane & 3) ^ ((lane >> 3) & 3)) << 3);
    unsigned ldsoff = (unsigned)(w < 4 ? 0 : 12288) + (unsigned)rowbase * 64;

    // read offsets (byte, within buffer): row*64 + ((lq ^ ((row>>1)&3))<<4)
    unsigned ssw = (unsigned)((lq ^ ((l15 >> 1) & 3)) << 4);
    unsigned aoff[6], boff[3];
    #pragma unroll
    for (int i = 0; i < 6; ++i)
        aoff[i] = (unsigned)(wr * 96 + i * 16 + l15) * 64 + ssw;
    #pragma unroll
    for (int j = 0; j < 3; ++j)
        boff[j] = 12288u + (unsigned)(wc * 48 + j * 16 + l15) * 64 + ssw;

    f32x4 acc[6][3];
    #pragma unroll
    for (int i = 0; i < 6; ++i)
        #pragma unroll
        for (int j = 0; j < 3; ++j)
            acc[i][j] = (f32x4){0.f, 0.f, 0.f, 0.f};

    #define STAGE(buf, kt)                                                     \
        {                                                                      \
            char* db = smem + (buf) * PAIR_B + ldsoff;                         \
            const unsigned short* gp = gsrc + (kt) * 32;                       \
            _Pragma("unroll")                                                  \
            for (int ci = 0; ci < 3; ++ci)                                     \
                gload16(gp + ci * 16 * CC, db + ci * 1024);                    \
        }

    #define COMPUTE(buf)                                                       \
        {                                                                      \
            const char* Bb = smem + (buf) * PAIR_B;                            \
            bf16x8 af[6], bfr[3];                                              \
            _Pragma("unroll")                                                  \
            for (int i = 0; i < 6; ++i)                                        \
                af[i] = *(const bf16x8*)(Bb + aoff[i]);                        \
            _Pragma("unroll")                                                  \
            for (int j = 0; j < 3; ++j)                                        \
                bfr[j] = *(const bf16x8*)(Bb + boff[j]);                       \
            _Pragma("unroll")                                                  \
            for (int i = 0; i < 6; ++i)                                        \
                _Pragma("unroll")                                              \
                for (int j = 0; j < 3; ++j)                                    \
                    acc[i][j] = __builtin_amdgcn_mfma_f32_16x16x32_bf16(       \
                        af[i], bfr[j], acc[i][j], 0, 0, 0);                    \
        }

    #define WAIT3() asm volatile("s_waitcnt vmcnt(3)" ::: "memory")
    #define WAIT0() asm volatile("s_waitcnt vmcnt(0)" ::: "memory")
    #define BAR()   { __builtin_amdgcn_sched_barrier(0); __builtin_amdgcn_s_barrier(); }

    STAGE(0, 0);
    STAGE(1, 1);                        // 6 loads in flight per wave

    #pragma unroll
    for (int kt = 0; kt < 16; ++kt) {
        if (kt < 15) { WAIT3(); } else { WAIT0(); }
        BAR();
        if (kt < 14) STAGE((kt + 2) % 3, kt + 2);
        COMPUTE(kt % 3);
    }

    // ---- epilogue (reduction buffers alias buffer 1; all K-loop reads done)
    float* colbuf = (float*)(smem + PAIR_B);          // [2][192]
    float* rowbuf = colbuf + 2 * HW;                  // [4][192]
    #pragma unroll
    for (int j = 0; j < 3; ++j) {
        float cm = -1e30f;
        #pragma unroll
        for (int i = 0; i < 6; ++i)
            #pragma unroll
            for (int r = 0; r < 4; ++r)
                cm = fmaxf(cm, acc[i][j][r]);
        cm = fmaxf(cm, __shfl_xor(cm, 16));
        cm = fmaxf(cm, __shfl_xor(cm, 32));
        if (lane < 16) colbuf[wr * HW + wc * 48 + j * 16 + l15] = cm;
    }
    #pragma unroll
    for (int i = 0; i < 6; ++i) {
        float rm[4];
        #pragma unroll
        for (int r = 0; r < 4; ++r) rm[r] = -1e30f;
        #pragma unroll
        for (int j = 0; j < 3; ++j)
            #pragma unroll
            for (int r = 0; r < 4; ++r)
                rm[r] = fmaxf(rm[r], acc[i][j][r]);
        #pragma unroll
        for (int msk = 1; msk <= 8; msk <<= 1)
            #pragma unroll
            for (int r = 0; r < 4; ++r)
                rm[r] = fmaxf(rm[r], __shfl_xor(rm[r], msk));
        if (l15 == 0) {
            #pragma unroll
            for (int r = 0; r < 4; ++r)
                rowbuf[wc * HW + wr * 96 + i * 16 + lq * 4 + r] = rm[r];
        }
    }
    __syncthreads();
    if (tid < HW) {
        float cmax = fmaxf(colbuf[tid], colbuf[HW + tid]);
        out[((size_t)g * B_ + p) * HW + tid] = cmax;
        float rmax = fmaxf(fmaxf(rowbuf[tid], rowbuf[HW + tid]),
                           fmaxf(rowbuf[2 * HW + tid], rowbuf[3 * HW + tid]));
        out[((size_t)p * B_ + g) * HW + tid] = rmax;
    }
}

extern "C" void kernel_launch(void* const* d_in, const int* in_sizes, int n_in,
                              void* d_out, int out_size, void* d_ws, size_t ws_size,
                              hipStream_t stream) {
    (void)in_sizes; (void)n_in; (void)out_size; (void)ws_size;
    const float* x  = (const float*)d_in[0];
    const float* Wq = (const float*)d_in[1];
    const float* bq = (const float*)d_in[2];
    const float* Wk = (const float*)d_in[3];
    const float* bk = (const float*)d_in[4];
    float* out = (float*)d_out;

    char* ws = (char*)d_ws;
    unsigned short* xt  = (unsigned short*)ws;                       // 6291456 B
    unsigned short* wqb = (unsigned short*)(ws + 6291456);           // 65536 B
    unsigned short* wkb = (unsigned short*)(ws + 6291456 + 65536);   // 65536 B
    unsigned short* qbuf = (unsigned short*)(ws + 6291456 + 131072); // 786432 B
    unsigned short* kbuf = (unsigned short*)(ws + 6291456 + 131072 + 786432);

    hipFuncSetAttribute((const void*)gram,
                        hipFuncAttributeMaxDynamicSharedMemorySize, SMEM_BYTES);

    k_transpose<<<dim3(96, 8), dim3(256), 0, stream>>>(x, xt);
    wcvt<<<dim3(64), dim3(256), 0, stream>>>(Wq, Wk, wqb, wkb);
    pam_qk<<<dim3(32, 4), dim3(256), 0, stream>>>(xt, wqb, wkb, bq, bk, qbuf, kbuf);
    pam_energy<<<dim3(32, 4), dim3(256), 0, stream>>>(qbuf, kbuf, out);
    gram<<<dim3(NTRI), dim3(512), SMEM_BYTES, stream>>>(xt, out);
}